// Round 12
// baseline (254.719 us; speedup 1.0000x reference)
//
#include <hip/hip_runtime.h>
#include <hip/hip_fp16.h>
#include <cstddef>

typedef _Float16 f16x8 __attribute__((ext_vector_type(8)));
typedef float f32x4 __attribute__((ext_vector_type(4)));
typedef unsigned short ushort8 __attribute__((ext_vector_type(8)));

// ================= setup stage 1: W fragment-pack (+layer blocks) ∥ dst bucket histogram =================
// B-fragment for mfma_f32_16x16x32_f16: lane l, elem i -> B[k][col],
//   k = kc*32 + (l>>4)*8 + i, col = nt*16 + (l&15)
__global__ __launch_bounds__(256) void k_setup1(const float* __restrict__ W0, const float* __restrict__ Wh,
                                                __half* __restrict__ WP, int nlayers,
                                                const int* __restrict__ dst, int* __restrict__ bcnt,
                                                int e, int nb) {
    __shared__ int lh[256];
    int t = threadIdx.x;
    if ((int)blockIdx.x < nlayers) {  // weight pack
        int layer = blockIdx.x;
        const float* W = (layer == 0) ? W0 : Wh + (size_t)(layer - 1) * 16384;
        __half* out = WP + (size_t)layer * 16384;
        for (int u = 0; u < 64; ++u) {
            int o = u * 256 + t;
            int i  = o & 7;
            int l  = (o >> 3) & 63;
            int kc = (o >> 9) & 3;
            int nt = o >> 11;
            int k   = kc * 32 + ((l >> 4) << 3) + i;
            int col = nt * 16 + (l & 15);
            out[o] = __float2half(W[k * 128 + col]);
        }
    } else {  // bucket histogram of dst>>8
        int bi = blockIdx.x - nlayers;
        lh[t] = 0;
        __syncthreads();
        for (int i = bi * 256 + t; i < e; i += nb * 256)
            atomicAdd(&lh[__builtin_nontemporal_load(&dst[i]) >> 8], 1);
        __syncthreads();
        if (lh[t] > 0) atomicAdd(&bcnt[t], lh[t]);
    }
}

// single block: exclusive scans of edge counts (bebase) and edge+selfloop counts (bcbase);
// init scatter cursors; rowptr[N] = E+N
__global__ __launch_bounds__(256) void k_bscan(const int* __restrict__ bcnt, int* __restrict__ bebase,
                                               int* __restrict__ bcbase, int* __restrict__ bcur,
                                               int* __restrict__ rowptr, int nbk, int n, int e) {
    __shared__ int se[256], sc[256];
    int t = threadIdx.x;
    int ec = (t < nbk) ? bcnt[t] : 0;
    int nodes = 0;
    if (t < nbk) {
        nodes = n - t * 256;
        if (nodes > 256) nodes = 256;
        if (nodes < 0) nodes = 0;
    }
    se[t] = ec;
    sc[t] = ec + nodes;
    __syncthreads();
    for (int off = 1; off < 256; off <<= 1) {
        int ve = (t >= off) ? se[t - off] : 0;
        int vc = (t >= off) ? sc[t - off] : 0;
        __syncthreads();
        se[t] += ve;
        sc[t] += vc;
        __syncthreads();
    }
    if (t < nbk) {
        bebase[t] = se[t] - ec;
        bcbase[t] = sc[t] - (ec + nodes);
        bcur[t]   = se[t] - ec;
    }
    if (t == 0) {
        bebase[nbk] = e;
        rowptr[n] = e + n;
    }
}

// scatter edges into bucket-contiguous storage; one global atomic per (block,bucket)
// packed entry: (src<<8) | (dst & 255)
__global__ __launch_bounds__(256) void k_bscatter(const int* __restrict__ src, const int* __restrict__ dst,
                                                  int* __restrict__ bcur, int* __restrict__ bedges, int e) {
    __shared__ int lh[256];
    __shared__ int gbase[256];
    int t = threadIdx.x;
    lh[t] = 0;
    __syncthreads();
    int base = blockIdx.x * 4096;
    int s_[16], d_[16];
#pragma unroll
    for (int u = 0; u < 16; ++u) {
        int j = base + u * 256 + t;
        if (j < e) {
            s_[u] = __builtin_nontemporal_load(&src[j]);
            d_[u] = __builtin_nontemporal_load(&dst[j]);
            atomicAdd(&lh[d_[u] >> 8], 1);
        } else {
            d_[u] = -1;
        }
    }
    __syncthreads();
    if (lh[t] > 0) gbase[t] = atomicAdd(&bcur[t], lh[t]);
    __syncthreads();
    lh[t] = 0;  // reuse as local cursor
    __syncthreads();
#pragma unroll
    for (int u = 0; u < 16; ++u) {
        if (d_[u] >= 0) {
            int bk = d_[u] >> 8;
            int lpos = atomicAdd(&lh[bk], 1);
            bedges[gbase[bk] + lpos] = (s_[u] << 8) | (d_[u] & 255);
        }
    }
}

// ================= setup stage 2 ∥ layer-0 GEMM =================
// blocks [0, nbk): per-bucket CSR build (rowptr/dinv/csr_s)
// blocks [nbk, ...): layer-0 GEMM from fp32 x, UNSCALED output (dinv[src] applied in k_agg<1>)
__global__ __launch_bounds__(256) void k_mix(const int* __restrict__ bedges, const int* __restrict__ bebase,
                                             const int* __restrict__ bcbase, int* __restrict__ rowptr,
                                             float* __restrict__ dinv, int* __restrict__ csr_s, int n,
                                             const float* __restrict__ X, const __half* __restrict__ WP,
                                             __half* __restrict__ O, int nbk) {
    __shared__ __half wl[16384];
    const int t = threadIdx.x;
    if ((int)blockIdx.x < nbk) {
        // ---- per-bucket CSR ----
        int* lh   = (int*)wl;
        int* lcur = lh + 256;
        int b = blockIdx.x;
        int n0 = b << 8;
        int nb = n - n0; if (nb > 256) nb = 256;
        int e0 = bebase[b], e1 = bebase[b + 1];
        int cb = bcbase[b];
        lh[t] = 0;
        __syncthreads();
        for (int i = e0 + t; i < e1; i += 256)
            atomicAdd(&lh[bedges[i] & 255], 1);
        __syncthreads();
        int deg = (t < nb) ? (lh[t] + 1) : 0;  // +1 self-loop
        __syncthreads();
        lh[t] = deg;
        __syncthreads();
        for (int off = 1; off < 256; off <<= 1) {
            int v = (t >= off) ? lh[t - off] : 0;
            __syncthreads();
            lh[t] += v;
            __syncthreads();
        }
        int lrp = lh[t] - deg;  // exclusive
        if (t < nb) {
            rowptr[n0 + t] = cb + lrp;
            dinv[n0 + t] = rsqrtf((float)deg);
        }
        lcur[t] = lrp;
        __syncthreads();
        for (int i = e0 + t; i < e1; i += 256) {
            int ed = bedges[i];
            int pos = cb + atomicAdd(&lcur[ed & 255], 1);
            csr_s[pos] = (int)((unsigned)ed >> 8);
        }
        if (t < nb) {
            int pos = cb + atomicAdd(&lcur[t], 1);
            csr_s[pos] = n0 + t;  // self-loop
        }
    } else {
        // ---- layer-0 GEMM (fp32 A, in-register cvt), unscaled fp16 out ----
#pragma unroll
        for (int u = 0; u < 8; ++u) {
            int idx = (u * 256 + t) * 8;
            *(ushort8*)&wl[idx] = *(const ushort8*)&WP[idx];
        }
        const int gb = blockIdx.x - nbk;
        const int wid = t >> 6, l = t & 63;
        const int row0 = gb * 128 + wid * 32;
        const int ar = l & 15, g = l >> 4;

        f16x8 a[2][4];
#pragma unroll
        for (int mt = 0; mt < 2; ++mt) {
            int row = row0 + mt * 16 + ar;
            int rc = min(row, n - 1);
#pragma unroll
            for (int kc = 0; kc < 4; ++kc) {
                f32x4 p0 = __builtin_nontemporal_load((const f32x4*)&X[(size_t)rc * 128 + kc * 32 + g * 8]);
                f32x4 p1 = __builtin_nontemporal_load((const f32x4*)&X[(size_t)rc * 128 + kc * 32 + g * 8 + 4]);
                f16x8 av;
                av[0] = (_Float16)p0[0]; av[1] = (_Float16)p0[1]; av[2] = (_Float16)p0[2]; av[3] = (_Float16)p0[3];
                av[4] = (_Float16)p1[0]; av[5] = (_Float16)p1[1]; av[6] = (_Float16)p1[2]; av[7] = (_Float16)p1[3];
                a[mt][kc] = av;
            }
        }
        __syncthreads();

#pragma unroll
        for (int nt = 0; nt < 8; ++nt) {
            f16x8 b[4];
#pragma unroll
            for (int kc = 0; kc < 4; ++kc)
                b[kc] = *(f16x8*)&wl[((nt * 4 + kc) * 64 + l) * 8];
#pragma unroll
            for (int mt = 0; mt < 2; ++mt) {
                f32x4 acc = {0.f, 0.f, 0.f, 0.f};
#pragma unroll
                for (int kc = 0; kc < 4; ++kc)
                    acc = __builtin_amdgcn_mfma_f32_16x16x32_f16(a[mt][kc], b[kc], acc, 0, 0, 0);
#pragma unroll
                for (int r = 0; r < 4; ++r) {
                    int orow = row0 + mt * 16 + g * 4 + r;
                    if (orow < n)
                        O[(size_t)orow * 128 + nt * 16 + ar] = __float2half(acc[r]);
                }
            }
        }
    }
}

// ================= MFMA GEMM (layers 1..3): O[r,:] = fp16( dinv[r] * (H[r,:] @ W) ) =================
__global__ __launch_bounds__(256) void k_gemm(const __half* __restrict__ H, const __half* __restrict__ WP,
                                              const float* __restrict__ dinv, __half* __restrict__ O,
                                              int n) {
    __shared__ __half wl[16384];
    const int t = threadIdx.x;
#pragma unroll
    for (int u = 0; u < 8; ++u) {
        int idx = (u * 256 + t) * 8;
        *(ushort8*)&wl[idx] = *(const ushort8*)&WP[idx];
    }
    const int wid = t >> 6, l = t & 63;
    const int row0 = blockIdx.x * 128 + wid * 32;
    const int ar = l & 15, g = l >> 4;

    f16x8 a[2][4];
    float dv[2][4];
#pragma unroll
    for (int mt = 0; mt < 2; ++mt) {
        int row = row0 + mt * 16 + ar;
        int rc = min(row, n - 1);
#pragma unroll
        for (int kc = 0; kc < 4; ++kc)
            a[mt][kc] = __builtin_nontemporal_load((const f16x8*)&H[(size_t)rc * 128 + kc * 32 + g * 8]);
#pragma unroll
        for (int r = 0; r < 4; ++r) {
            int orow = row0 + mt * 16 + g * 4 + r;
            dv[mt][r] = dinv[min(orow, n - 1)];
        }
    }
    __syncthreads();

#pragma unroll
    for (int nt = 0; nt < 8; ++nt) {
        f16x8 b[4];
#pragma unroll
        for (int kc = 0; kc < 4; ++kc)
            b[kc] = *(f16x8*)&wl[((nt * 4 + kc) * 64 + l) * 8];
#pragma unroll
        for (int mt = 0; mt < 2; ++mt) {
            f32x4 acc = {0.f, 0.f, 0.f, 0.f};
#pragma unroll
            for (int kc = 0; kc < 4; ++kc)
                acc = __builtin_amdgcn_mfma_f32_16x16x32_f16(a[mt][kc], b[kc], acc, 0, 0, 0);
#pragma unroll
            for (int r = 0; r < 4; ++r) {
                int orow = row0 + mt * 16 + g * 4 + r;
                if (orow < n)
                    O[(size_t)orow * 128 + nt * 16 + ar] = __float2half(acc[r] * dv[mt][r]);
            }
        }
    }
}

// ================= aggregation: h[v] = relu(dinv[v]*sum w_s*XW[src] + bias) -> fp16 =================
// one wave per node. Lane = (g=lane>>4, fs=lane&15): each f16x8 load (16B) gathers FOUR neighbor
// rows per wave instruction. Row pairs pre-added in fp16 (v_pk_add_f16) before f32 accumulate
// (~1.5x VALU cut; +~sqrt(2)x quantization noise, within budget). cs loads and Hn stores are
// non-temporal so the 12.8MB gather target keeps L2 residency.
template <int SCALE_SRC>
__global__ __launch_bounds__(256) void k_agg(const __half* __restrict__ XW, const int* __restrict__ cs,
                                             const int* __restrict__ rp, const float* __restrict__ dinv,
                                             const float* __restrict__ bias, __half* __restrict__ Hn, int n) {
    int wid  = (blockIdx.x * 256 + threadIdx.x) >> 6;
    int lane = threadIdx.x & 63;
    if (wid >= n) return;
    int s = rp[wid], e = rp[wid + 1];
    const int g = lane >> 4, fs = lane & 15;
    float acc0[8], acc1[8];
#pragma unroll
    for (int k = 0; k < 8; ++k) { acc0[k] = 0.f; acc1[k] = 0.f; }
    for (int base = s; base < e; base += 64) {
        int m = e - base;
        if (m > 64) m = 64;
        int myi = (lane < m) ? __builtin_nontemporal_load(&cs[base + lane]) : 0;
#pragma unroll
        for (int jj = 0; jj < 8; ++jj) {
            const int j = jj * 8;
            if (j >= m) break;  // wave-uniform
            int ia = __shfl(myi, j + g);
            int ib = __shfl(myi, j + 4 + g);
            bool ha = (j + g) < m;
            bool hb = (j + 4 + g) < m;   // hb implies ha
            f16x8 va = {}, vb = {};
            if (ha) va = *(const f16x8*)&XW[(size_t)ia * 128 + fs * 8];
            if (hb) vb = *(const f16x8*)&XW[(size_t)ib * 128 + fs * 8];
            if (SCALE_SRC) {
                if (ha) {
                    float wsa = dinv[ia];
#pragma unroll
                    for (int k = 0; k < 8; ++k) acc0[k] = fmaf(wsa, (float)va[k], acc0[k]);
                }
                if (hb) {
                    float wsb = dinv[ib];
#pragma unroll
                    for (int k = 0; k < 8; ++k) acc1[k] = fmaf(wsb, (float)vb[k], acc1[k]);
                }
            } else {
                if (hb) {
                    f16x8 sv = va + vb;  // v_pk_add_f16 x4
                    if (jj & 1) {
#pragma unroll
                        for (int k = 0; k < 8; ++k) acc1[k] += (float)sv[k];
                    } else {
#pragma unroll
                        for (int k = 0; k < 8; ++k) acc0[k] += (float)sv[k];
                    }
                } else if (ha) {
#pragma unroll
                    for (int k = 0; k < 8; ++k) acc0[k] += (float)va[k];
                }
            }
        }
    }
#pragma unroll
    for (int k = 0; k < 8; ++k) acc0[k] += acc1[k];
#pragma unroll
    for (int k = 0; k < 8; ++k) acc0[k] += __shfl_xor(acc0[k], 16);
#pragma unroll
    for (int k = 0; k < 8; ++k) acc0[k] += __shfl_xor(acc0[k], 32);
    if (g == 0) {
        float dvv = dinv[wid];
        float4 bb0 = *(const float4*)&bias[fs * 8];
        float4 bb1 = *(const float4*)&bias[fs * 8 + 4];
        float bb[8] = {bb0.x, bb0.y, bb0.z, bb0.w, bb1.x, bb1.y, bb1.z, bb1.w};
        f16x8 o;
#pragma unroll
        for (int k = 0; k < 8; ++k)
            o[k] = (_Float16)fmaxf(fmaf(acc0[k], dvv, bb[k]), 0.f);
        __builtin_nontemporal_store(o, (f16x8*)&Hn[(size_t)wid * 128 + fs * 8]);
    }
}

// ================= fused pooling + head: one block per graph =================
__global__ __launch_bounds__(256) void k_poolhead(const __half* __restrict__ H, const int* __restrict__ batch,
                                                  const float* __restrict__ w1, const float* __restrict__ b1,
                                                  const float* __restrict__ w2, const float* __restrict__ b2,
                                                  float* __restrict__ out, int n) {
    __shared__ float lsum[16][128];
    __shared__ float lmax[16][128];
    __shared__ float gv[384];
    __shared__ float o1[128];
    __shared__ int bnd[2];
    int g = blockIdx.x, t = threadIdx.x;
    if (t < 2) {
        int key = g + t;
        int lo = 0, hi = n;
        while (lo < hi) {
            int mid = (lo + hi) >> 1;
            if (batch[mid] < key) lo = mid + 1; else hi = mid;
        }
        bnd[t] = lo;
    }
    __syncthreads();
    const int s = bnd[0], e = bnd[1];
    const int rg = t >> 4, fb = t & 15;
    float sum8[8], max8[8];
#pragma unroll
    for (int j = 0; j < 8; ++j) { sum8[j] = 0.f; max8[j] = 0.f; }  // h>=0: 0-init == isfinite guard
    for (int r = s + rg; r < e; r += 16) {
        f16x8 v = __builtin_nontemporal_load((const f16x8*)&H[(size_t)r * 128 + fb * 8]);
#pragma unroll
        for (int j = 0; j < 8; ++j) {
            float x = (float)v[j];
            sum8[j] += x;
            max8[j] = fmaxf(max8[j], x);
        }
    }
#pragma unroll
    for (int j = 0; j < 8; ++j) {
        lsum[rg][fb * 8 + j] = sum8[j];
        lmax[rg][fb * 8 + j] = max8[j];
    }
    __syncthreads();
    if (t < 128) {
        float sum = 0.f, mx = 0.f;
#pragma unroll
        for (int r = 0; r < 16; ++r) {
            sum += lsum[r][t];
            mx = fmaxf(mx, lmax[r][t]);
        }
        float cnt = (float)(e - s);
        gv[t]       = sum;
        gv[128 + t] = sum / fmaxf(cnt, 1.f);
        gv[256 + t] = mx;
    }
    __syncthreads();
    if (t < 128) {
        float acc = b1[t];
#pragma unroll 8
        for (int k = 0; k < 384; ++k) acc = fmaf(gv[k], w1[k * 128 + t], acc);
        o1[t] = fmaxf(acc, 0.f);
    }
    __syncthreads();
    if (t < 64) {
        float p0 = o1[t] * w2[t * 2 + 0] + o1[t + 64] * w2[(t + 64) * 2 + 0];
        float p1 = o1[t] * w2[t * 2 + 1] + o1[t + 64] * w2[(t + 64) * 2 + 1];
        for (int off = 32; off > 0; off >>= 1) {
            p0 += __shfl_down(p0, off);
            p1 += __shfl_down(p1, off);
        }
        if (t == 0) {
            float l0 = p0 + b2[0], l1 = p1 + b2[1];
            float m = fmaxf(l0, l1);
            float lse = m + logf(expf(l0 - m) + expf(l1 - m));
            out[g * 2 + 0] = l0 - lse;
            out[g * 2 + 1] = l1 - lse;
        }
    }
}

// ================= launcher =================

extern "C" void kernel_launch(void* const* d_in, const int* in_sizes, int n_in,
                              void* d_out, int out_size, void* d_ws, size_t ws_size,
                              hipStream_t stream) {
    const float* x     = (const float*)d_in[0];
    const int*   ei    = (const int*)d_in[1];
    const int*   batch = (const int*)d_in[2];
    const float* W0    = (const float*)d_in[3];
    const float* b0    = (const float*)d_in[4];
    const float* Wh    = (const float*)d_in[5];
    const float* bh    = (const float*)d_in[6];
    const float* l1w   = (const float*)d_in[7];
    const float* l1b   = (const float*)d_in[8];
    const float* l2w   = (const float*)d_in[9];
    const float* l2b   = (const float*)d_in[10];
    float* out = (float*)d_out;

    const int N  = in_sizes[0] / 128;
    const int E  = in_sizes[1] / 2;
    const int G  = out_size / 2;
    const int LX = in_sizes[5] / (128 * 128);
    const int NB = (N + 255) / 256;  // buckets (<=256 assumed, N<=65536)

    const int* src = ei;
    const int* dst = ei + E;

    char* p = (char*)d_ws;
    auto alloc = [&](size_t bytes) -> void* {
        void* r = (void*)p;
        p += (bytes + 255) & ~(size_t)255;
        return r;
    };
    int*    rowptr = (int*)alloc((size_t)(N + 1) * 4);
    float*  dinv   = (float*)alloc((size_t)N * 4);
    int*    bcnt   = (int*)alloc(1040);
    int*    bebase = (int*)alloc(1040);
    int*    bcbase = (int*)alloc(1040);
    int*    bcur   = (int*)alloc(1040);
    int*    csr_s  = (int*)alloc((size_t)(E + N) * 4);
    int*    bedges = (int*)alloc((size_t)E * 4);
    __half* h16    = (__half*)alloc((size_t)N * 128 * 2);
    __half* xw16   = (__half*)alloc((size_t)N * 128 * 2);
    __half* wp     = (__half*)alloc((size_t)(LX + 1) * 16384 * 2);

    const int gemmBlocks = (N + 127) / 128;
    const int aggBlocks  = (N + 3) / 4;

    // --- setup: bcnt zero; [wprep ∥ bhist]; scan; scatter; [bcsr ∥ layer-0 gemm] ---
    (void)hipMemsetAsync(bcnt, 0, 1024, stream);
    k_setup1<<<(LX + 1) + NB, 256, 0, stream>>>(W0, Wh, wp, LX + 1, dst, bcnt, E, NB);
    k_bscan<<<1, 256, 0, stream>>>(bcnt, bebase, bcbase, bcur, rowptr, NB, N, E);
    k_bscatter<<<(E + 4095) / 4096, 256, 0, stream>>>(src, dst, bcur, bedges, E);
    k_mix<<<NB + gemmBlocks, 256, 0, stream>>>(bedges, bebase, bcbase, rowptr, dinv, csr_s, N,
                                               x, wp, xw16, NB);

    // --- layer 0 aggregation (applies dinv[src] per edge), then layers 1..3 ---
    k_agg<1><<<aggBlocks, 256, 0, stream>>>(xw16, csr_s, rowptr, dinv, b0, h16, N);
    for (int l = 0; l < LX; ++l) {
        k_gemm<<<gemmBlocks, 256, 0, stream>>>(h16, wp + (size_t)(l + 1) * 16384, dinv, xw16, N);
        k_agg<0><<<aggBlocks, 256, 0, stream>>>(xw16, csr_s, rowptr, dinv, bh + (size_t)l * 128, h16, N);
    }

    // --- fused pooling + head ---
    k_poolhead<<<G, 256, 0, stream>>>(h16, batch, l1w, l1b, l2w, l2b, out, N);
}

// Round 13
// 237.180 us; speedup vs baseline: 1.0739x; 1.0739x over previous
//
#include <hip/hip_runtime.h>
#include <hip/hip_fp16.h>
#include <cstddef>

typedef _Float16 f16x8 __attribute__((ext_vector_type(8)));
typedef float f32x4 __attribute__((ext_vector_type(4)));
typedef unsigned short ushort8 __attribute__((ext_vector_type(8)));

// ================= setup stage 1: W fragment-pack (+layer blocks) ∥ dst bucket histogram =================
// B-fragment for mfma_f32_16x16x32_f16: lane l, elem i -> B[k][col],
//   k = kc*32 + (l>>4)*8 + i, col = nt*16 + (l&15)
__global__ __launch_bounds__(256) void k_setup1(const float* __restrict__ W0, const float* __restrict__ Wh,
                                                __half* __restrict__ WP, int nlayers,
                                                const int* __restrict__ dst, int* __restrict__ bcnt,
                                                int e, int nb) {
    __shared__ int lh[256];
    int t = threadIdx.x;
    if ((int)blockIdx.x < nlayers) {  // weight pack
        int layer = blockIdx.x;
        const float* W = (layer == 0) ? W0 : Wh + (size_t)(layer - 1) * 16384;
        __half* out = WP + (size_t)layer * 16384;
        for (int u = 0; u < 64; ++u) {
            int o = u * 256 + t;
            int i  = o & 7;
            int l  = (o >> 3) & 63;
            int kc = (o >> 9) & 3;
            int nt = o >> 11;
            int k   = kc * 32 + ((l >> 4) << 3) + i;
            int col = nt * 16 + (l & 15);
            out[o] = __float2half(W[k * 128 + col]);
        }
    } else {  // bucket histogram of dst>>8
        int bi = blockIdx.x - nlayers;
        lh[t] = 0;
        __syncthreads();
        for (int i = bi * 256 + t; i < e; i += nb * 256)
            atomicAdd(&lh[dst[i] >> 8], 1);
        __syncthreads();
        if (lh[t] > 0) atomicAdd(&bcnt[t], lh[t]);
    }
}

// single block: exclusive scans of edge counts (bebase) and edge+selfloop counts (bcbase);
// init scatter cursors; rowptr[N] = E+N
__global__ __launch_bounds__(256) void k_bscan(const int* __restrict__ bcnt, int* __restrict__ bebase,
                                               int* __restrict__ bcbase, int* __restrict__ bcur,
                                               int* __restrict__ rowptr, int nbk, int n, int e) {
    __shared__ int se[256], sc[256];
    int t = threadIdx.x;
    int ec = (t < nbk) ? bcnt[t] : 0;
    int nodes = 0;
    if (t < nbk) {
        nodes = n - t * 256;
        if (nodes > 256) nodes = 256;
        if (nodes < 0) nodes = 0;
    }
    se[t] = ec;
    sc[t] = ec + nodes;
    __syncthreads();
    for (int off = 1; off < 256; off <<= 1) {
        int ve = (t >= off) ? se[t - off] : 0;
        int vc = (t >= off) ? sc[t - off] : 0;
        __syncthreads();
        se[t] += ve;
        sc[t] += vc;
        __syncthreads();
    }
    if (t < nbk) {
        bebase[t] = se[t] - ec;
        bcbase[t] = sc[t] - (ec + nodes);
        bcur[t]   = se[t] - ec;
    }
    if (t == 0) {
        bebase[nbk] = e;
        rowptr[n] = e + n;
    }
}

// scatter edges into bucket-contiguous storage; one global atomic per (block,bucket)
// packed entry: (src<<8) | (dst & 255)
__global__ __launch_bounds__(256) void k_bscatter(const int* __restrict__ src, const int* __restrict__ dst,
                                                  int* __restrict__ bcur, int* __restrict__ bedges, int e) {
    __shared__ int lh[256];
    __shared__ int gbase[256];
    int t = threadIdx.x;
    lh[t] = 0;
    __syncthreads();
    int base = blockIdx.x * 4096;
    int s_[16], d_[16];
#pragma unroll
    for (int u = 0; u < 16; ++u) {
        int j = base + u * 256 + t;
        if (j < e) {
            s_[u] = src[j];
            d_[u] = dst[j];
            atomicAdd(&lh[d_[u] >> 8], 1);
        } else {
            d_[u] = -1;
        }
    }
    __syncthreads();
    if (lh[t] > 0) gbase[t] = atomicAdd(&bcur[t], lh[t]);
    __syncthreads();
    lh[t] = 0;  // reuse as local cursor
    __syncthreads();
#pragma unroll
    for (int u = 0; u < 16; ++u) {
        if (d_[u] >= 0) {
            int bk = d_[u] >> 8;
            int lpos = atomicAdd(&lh[bk], 1);
            bedges[gbase[bk] + lpos] = (s_[u] << 8) | (d_[u] & 255);
        }
    }
}

// ================= setup stage 2 ∥ layer-0 GEMM =================
// blocks [0, nbk): per-bucket CSR build (rowptr/dinv/csr_s)
// blocks [nbk, ...): layer-0 GEMM from fp32 x, UNSCALED output (dinv[src] applied in k_agg<1>)
__global__ __launch_bounds__(256) void k_mix(const int* __restrict__ bedges, const int* __restrict__ bebase,
                                             const int* __restrict__ bcbase, int* __restrict__ rowptr,
                                             float* __restrict__ dinv, int* __restrict__ csr_s, int n,
                                             const float* __restrict__ X, const __half* __restrict__ WP,
                                             __half* __restrict__ O, int nbk) {
    __shared__ __half wl[16384];
    const int t = threadIdx.x;
    if ((int)blockIdx.x < nbk) {
        // ---- per-bucket CSR ----
        int* lh   = (int*)wl;
        int* lcur = lh + 256;
        int b = blockIdx.x;
        int n0 = b << 8;
        int nb = n - n0; if (nb > 256) nb = 256;
        int e0 = bebase[b], e1 = bebase[b + 1];
        int cb = bcbase[b];
        lh[t] = 0;
        __syncthreads();
        for (int i = e0 + t; i < e1; i += 256)
            atomicAdd(&lh[bedges[i] & 255], 1);
        __syncthreads();
        int deg = (t < nb) ? (lh[t] + 1) : 0;  // +1 self-loop
        __syncthreads();
        lh[t] = deg;
        __syncthreads();
        for (int off = 1; off < 256; off <<= 1) {
            int v = (t >= off) ? lh[t - off] : 0;
            __syncthreads();
            lh[t] += v;
            __syncthreads();
        }
        int lrp = lh[t] - deg;  // exclusive
        if (t < nb) {
            rowptr[n0 + t] = cb + lrp;
            dinv[n0 + t] = rsqrtf((float)deg);
        }
        lcur[t] = lrp;
        __syncthreads();
        for (int i = e0 + t; i < e1; i += 256) {
            int ed = bedges[i];
            int pos = cb + atomicAdd(&lcur[ed & 255], 1);
            csr_s[pos] = (int)((unsigned)ed >> 8);
        }
        if (t < nb) {
            int pos = cb + atomicAdd(&lcur[t], 1);
            csr_s[pos] = n0 + t;  // self-loop
        }
    } else {
        // ---- layer-0 GEMM (fp32 A, in-register cvt), unscaled fp16 out ----
#pragma unroll
        for (int u = 0; u < 8; ++u) {
            int idx = (u * 256 + t) * 8;
            *(ushort8*)&wl[idx] = *(const ushort8*)&WP[idx];
        }
        const int gb = blockIdx.x - nbk;
        const int wid = t >> 6, l = t & 63;
        const int row0 = gb * 128 + wid * 32;
        const int ar = l & 15, g = l >> 4;

        f16x8 a[2][4];
#pragma unroll
        for (int mt = 0; mt < 2; ++mt) {
            int row = row0 + mt * 16 + ar;
            int rc = min(row, n - 1);
#pragma unroll
            for (int kc = 0; kc < 4; ++kc) {
                f32x4 p0 = *(const f32x4*)&X[(size_t)rc * 128 + kc * 32 + g * 8];
                f32x4 p1 = *(const f32x4*)&X[(size_t)rc * 128 + kc * 32 + g * 8 + 4];
                f16x8 av;
                av[0] = (_Float16)p0[0]; av[1] = (_Float16)p0[1]; av[2] = (_Float16)p0[2]; av[3] = (_Float16)p0[3];
                av[4] = (_Float16)p1[0]; av[5] = (_Float16)p1[1]; av[6] = (_Float16)p1[2]; av[7] = (_Float16)p1[3];
                a[mt][kc] = av;
            }
        }
        __syncthreads();

#pragma unroll
        for (int nt = 0; nt < 8; ++nt) {
            f16x8 b[4];
#pragma unroll
            for (int kc = 0; kc < 4; ++kc)
                b[kc] = *(f16x8*)&wl[((nt * 4 + kc) * 64 + l) * 8];
#pragma unroll
            for (int mt = 0; mt < 2; ++mt) {
                f32x4 acc = {0.f, 0.f, 0.f, 0.f};
#pragma unroll
                for (int kc = 0; kc < 4; ++kc)
                    acc = __builtin_amdgcn_mfma_f32_16x16x32_f16(a[mt][kc], b[kc], acc, 0, 0, 0);
#pragma unroll
                for (int r = 0; r < 4; ++r) {
                    int orow = row0 + mt * 16 + g * 4 + r;
                    if (orow < n)
                        O[(size_t)orow * 128 + nt * 16 + ar] = __float2half(acc[r]);
                }
            }
        }
    }
}

// ================= MFMA GEMM (layers 1..3): O[r,:] = fp16( dinv[r] * (H[r,:] @ W) ) =================
__global__ __launch_bounds__(256) void k_gemm(const __half* __restrict__ H, const __half* __restrict__ WP,
                                              const float* __restrict__ dinv, __half* __restrict__ O,
                                              int n) {
    __shared__ __half wl[16384];
    const int t = threadIdx.x;
#pragma unroll
    for (int u = 0; u < 8; ++u) {
        int idx = (u * 256 + t) * 8;
        *(ushort8*)&wl[idx] = *(const ushort8*)&WP[idx];
    }
    const int wid = t >> 6, l = t & 63;
    const int row0 = blockIdx.x * 128 + wid * 32;
    const int ar = l & 15, g = l >> 4;

    f16x8 a[2][4];
    float dv[2][4];
#pragma unroll
    for (int mt = 0; mt < 2; ++mt) {
        int row = row0 + mt * 16 + ar;
        int rc = min(row, n - 1);
#pragma unroll
        for (int kc = 0; kc < 4; ++kc)
            a[mt][kc] = *(const f16x8*)&H[(size_t)rc * 128 + kc * 32 + g * 8];
#pragma unroll
        for (int r = 0; r < 4; ++r) {
            int orow = row0 + mt * 16 + g * 4 + r;
            dv[mt][r] = dinv[min(orow, n - 1)];
        }
    }
    __syncthreads();

#pragma unroll
    for (int nt = 0; nt < 8; ++nt) {
        f16x8 b[4];
#pragma unroll
        for (int kc = 0; kc < 4; ++kc)
            b[kc] = *(f16x8*)&wl[((nt * 4 + kc) * 64 + l) * 8];
#pragma unroll
        for (int mt = 0; mt < 2; ++mt) {
            f32x4 acc = {0.f, 0.f, 0.f, 0.f};
#pragma unroll
            for (int kc = 0; kc < 4; ++kc)
                acc = __builtin_amdgcn_mfma_f32_16x16x32_f16(a[mt][kc], b[kc], acc, 0, 0, 0);
#pragma unroll
            for (int r = 0; r < 4; ++r) {
                int orow = row0 + mt * 16 + g * 4 + r;
                if (orow < n)
                    O[(size_t)orow * 128 + nt * 16 + ar] = __float2half(acc[r] * dv[mt][r]);
            }
        }
    }
}

// ================= aggregation: h[v] = relu(dinv[v]*sum w_s*XW[src] + bias) -> fp16 =================
// one wave per node. Lane = (g=lane>>4, fs=lane&15): each f16x8 load (16B) gathers FOUR neighbor
// rows per wave instruction. Row pairs pre-added in fp16 (v_pk_add_f16) before f32 accumulate
// (~1.5x VALU cut; +~sqrt(2)x quantization noise, within budget — r12 validated absmax unchanged).
template <int SCALE_SRC>
__global__ __launch_bounds__(256) void k_agg(const __half* __restrict__ XW, const int* __restrict__ cs,
                                             const int* __restrict__ rp, const float* __restrict__ dinv,
                                             const float* __restrict__ bias, __half* __restrict__ Hn, int n) {
    int wid  = (blockIdx.x * 256 + threadIdx.x) >> 6;
    int lane = threadIdx.x & 63;
    if (wid >= n) return;
    int s = rp[wid], e = rp[wid + 1];
    const int g = lane >> 4, fs = lane & 15;
    float acc0[8], acc1[8];
#pragma unroll
    for (int k = 0; k < 8; ++k) { acc0[k] = 0.f; acc1[k] = 0.f; }
    for (int base = s; base < e; base += 64) {
        int m = e - base;
        if (m > 64) m = 64;
        int myi = (lane < m) ? cs[base + lane] : 0;
#pragma unroll
        for (int jj = 0; jj < 8; ++jj) {
            const int j = jj * 8;
            if (j >= m) break;  // wave-uniform
            int ia = __shfl(myi, j + g);
            int ib = __shfl(myi, j + 4 + g);
            bool ha = (j + g) < m;
            bool hb = (j + 4 + g) < m;   // hb implies ha
            f16x8 va = {}, vb = {};
            if (ha) va = *(const f16x8*)&XW[(size_t)ia * 128 + fs * 8];
            if (hb) vb = *(const f16x8*)&XW[(size_t)ib * 128 + fs * 8];
            if (SCALE_SRC) {
                if (ha) {
                    float wsa = dinv[ia];
#pragma unroll
                    for (int k = 0; k < 8; ++k) acc0[k] = fmaf(wsa, (float)va[k], acc0[k]);
                }
                if (hb) {
                    float wsb = dinv[ib];
#pragma unroll
                    for (int k = 0; k < 8; ++k) acc1[k] = fmaf(wsb, (float)vb[k], acc1[k]);
                }
            } else {
                if (hb) {
                    f16x8 sv = va + vb;  // v_pk_add_f16 x4
                    if (jj & 1) {
#pragma unroll
                        for (int k = 0; k < 8; ++k) acc1[k] += (float)sv[k];
                    } else {
#pragma unroll
                        for (int k = 0; k < 8; ++k) acc0[k] += (float)sv[k];
                    }
                } else if (ha) {
#pragma unroll
                    for (int k = 0; k < 8; ++k) acc0[k] += (float)va[k];
                }
            }
        }
    }
#pragma unroll
    for (int k = 0; k < 8; ++k) acc0[k] += acc1[k];
#pragma unroll
    for (int k = 0; k < 8; ++k) acc0[k] += __shfl_xor(acc0[k], 16);
#pragma unroll
    for (int k = 0; k < 8; ++k) acc0[k] += __shfl_xor(acc0[k], 32);
    if (g == 0) {
        float dvv = dinv[wid];
        float4 bb0 = *(const float4*)&bias[fs * 8];
        float4 bb1 = *(const float4*)&bias[fs * 8 + 4];
        float bb[8] = {bb0.x, bb0.y, bb0.z, bb0.w, bb1.x, bb1.y, bb1.z, bb1.w};
        f16x8 o;
#pragma unroll
        for (int k = 0; k < 8; ++k)
            o[k] = (_Float16)fmaxf(fmaf(acc0[k], dvv, bb[k]), 0.f);
        *(f16x8*)&Hn[(size_t)wid * 128 + fs * 8] = o;
    }
}

// ================= fused pooling + head: one block per graph =================
__global__ __launch_bounds__(256) void k_poolhead(const __half* __restrict__ H, const int* __restrict__ batch,
                                                  const float* __restrict__ w1, const float* __restrict__ b1,
                                                  const float* __restrict__ w2, const float* __restrict__ b2,
                                                  float* __restrict__ out, int n) {
    __shared__ float lsum[16][128];
    __shared__ float lmax[16][128];
    __shared__ float gv[384];
    __shared__ float o1[128];
    __shared__ int bnd[2];
    int g = blockIdx.x, t = threadIdx.x;
    if (t < 2) {
        int key = g + t;
        int lo = 0, hi = n;
        while (lo < hi) {
            int mid = (lo + hi) >> 1;
            if (batch[mid] < key) lo = mid + 1; else hi = mid;
        }
        bnd[t] = lo;
    }
    __syncthreads();
    const int s = bnd[0], e = bnd[1];
    const int rg = t >> 4, fb = t & 15;
    float sum8[8], max8[8];
#pragma unroll
    for (int j = 0; j < 8; ++j) { sum8[j] = 0.f; max8[j] = 0.f; }  // h>=0: 0-init == isfinite guard
    for (int r = s + rg; r < e; r += 16) {
        f16x8 v = *(const f16x8*)&H[(size_t)r * 128 + fb * 8];
#pragma unroll
        for (int j = 0; j < 8; ++j) {
            float x = (float)v[j];
            sum8[j] += x;
            max8[j] = fmaxf(max8[j], x);
        }
    }
#pragma unroll
    for (int j = 0; j < 8; ++j) {
        lsum[rg][fb * 8 + j] = sum8[j];
        lmax[rg][fb * 8 + j] = max8[j];
    }
    __syncthreads();
    if (t < 128) {
        float sum = 0.f, mx = 0.f;
#pragma unroll
        for (int r = 0; r < 16; ++r) {
            sum += lsum[r][t];
            mx = fmaxf(mx, lmax[r][t]);
        }
        float cnt = (float)(e - s);
        gv[t]       = sum;
        gv[128 + t] = sum / fmaxf(cnt, 1.f);
        gv[256 + t] = mx;
    }
    __syncthreads();
    if (t < 128) {
        float acc = b1[t];
#pragma unroll 8
        for (int k = 0; k < 384; ++k) acc = fmaf(gv[k], w1[k * 128 + t], acc);
        o1[t] = fmaxf(acc, 0.f);
    }
    __syncthreads();
    if (t < 64) {
        float p0 = o1[t] * w2[t * 2 + 0] + o1[t + 64] * w2[(t + 64) * 2 + 0];
        float p1 = o1[t] * w2[t * 2 + 1] + o1[t + 64] * w2[(t + 64) * 2 + 1];
        for (int off = 32; off > 0; off >>= 1) {
            p0 += __shfl_down(p0, off);
            p1 += __shfl_down(p1, off);
        }
        if (t == 0) {
            float l0 = p0 + b2[0], l1 = p1 + b2[1];
            float m = fmaxf(l0, l1);
            float lse = m + logf(expf(l0 - m) + expf(l1 - m));
            out[g * 2 + 0] = l0 - lse;
            out[g * 2 + 1] = l1 - lse;
        }
    }
}

// ================= launcher =================

extern "C" void kernel_launch(void* const* d_in, const int* in_sizes, int n_in,
                              void* d_out, int out_size, void* d_ws, size_t ws_size,
                              hipStream_t stream) {
    const float* x     = (const float*)d_in[0];
    const int*   ei    = (const int*)d_in[1];
    const int*   batch = (const int*)d_in[2];
    const float* W0    = (const float*)d_in[3];
    const float* b0    = (const float*)d_in[4];
    const float* Wh    = (const float*)d_in[5];
    const float* bh    = (const float*)d_in[6];
    const float* l1w   = (const float*)d_in[7];
    const float* l1b   = (const float*)d_in[8];
    const float* l2w   = (const float*)d_in[9];
    const float* l2b   = (const float*)d_in[10];
    float* out = (float*)d_out;

    const int N  = in_sizes[0] / 128;
    const int E  = in_sizes[1] / 2;
    const int G  = out_size / 2;
    const int LX = in_sizes[5] / (128 * 128);
    const int NB = (N + 255) / 256;  // buckets (<=256 assumed, N<=65536)

    const int* src = ei;
    const int* dst = ei + E;

    char* p = (char*)d_ws;
    auto alloc = [&](size_t bytes) -> void* {
        void* r = (void*)p;
        p += (bytes + 255) & ~(size_t)255;
        return r;
    };
    int*    rowptr = (int*)alloc((size_t)(N + 1) * 4);
    float*  dinv   = (float*)alloc((size_t)N * 4);
    int*    bcnt   = (int*)alloc(1040);
    int*    bebase = (int*)alloc(1040);
    int*    bcbase = (int*)alloc(1040);
    int*    bcur   = (int*)alloc(1040);
    int*    csr_s  = (int*)alloc((size_t)(E + N) * 4);
    int*    bedges = (int*)alloc((size_t)E * 4);
    __half* h16    = (__half*)alloc((size_t)N * 128 * 2);
    __half* xw16   = (__half*)alloc((size_t)N * 128 * 2);
    __half* wp     = (__half*)alloc((size_t)(LX + 1) * 16384 * 2);

    const int gemmBlocks = (N + 127) / 128;
    const int aggBlocks  = (N + 3) / 4;

    // --- setup: bcnt zero; [wprep ∥ bhist]; scan; scatter; [bcsr ∥ layer-0 gemm] ---
    (void)hipMemsetAsync(bcnt, 0, 1024, stream);
    k_setup1<<<(LX + 1) + NB, 256, 0, stream>>>(W0, Wh, wp, LX + 1, dst, bcnt, E, NB);
    k_bscan<<<1, 256, 0, stream>>>(bcnt, bebase, bcbase, bcur, rowptr, NB, N, E);
    k_bscatter<<<(E + 4095) / 4096, 256, 0, stream>>>(src, dst, bcur, bedges, E);
    k_mix<<<NB + gemmBlocks, 256, 0, stream>>>(bedges, bebase, bcbase, rowptr, dinv, csr_s, N,
                                               x, wp, xw16, NB);

    // --- layer 0 aggregation (applies dinv[src] per edge), then layers 1..3 ---
    k_agg<1><<<aggBlocks, 256, 0, stream>>>(xw16, csr_s, rowptr, dinv, b0, h16, N);
    for (int l = 0; l < LX; ++l) {
        k_gemm<<<gemmBlocks, 256, 0, stream>>>(h16, wp + (size_t)(l + 1) * 16384, dinv, xw16, N);
        k_agg<0><<<aggBlocks, 256, 0, stream>>>(xw16, csr_s, rowptr, dinv, bh + (size_t)l * 128, h16, N);
    }

    // --- fused pooling + head ---
    k_poolhead<<<G, 256, 0, stream>>>(h16, batch, l1w, l1b, l2w, l2b, out, N);
}